// Round 19
// baseline (99.540 us; speedup 1.0000x reference)
//
#include <hip/hip_runtime.h>
#include <hip/hip_fp16.h>

typedef __attribute__((ext_vector_type(8))) _Float16 half8;
typedef __attribute__((ext_vector_type(4))) float f32x4;

union U2H2 { unsigned int u; __half2 h; };

static __device__ __forceinline__ unsigned int pack2h(float a, float b) {
    U2H2 c; c.h = __floats2half2_rn(a, b); return c.u;
}
static __device__ __forceinline__ __half2 u_as_h2(unsigned int u) {
    U2H2 c; c.u = u; return c.h;
}
static __device__ __forceinline__ __half2 hi16(unsigned int u) {
    return u_as_h2(__builtin_amdgcn_perm(u, u, 0x03020302u));
}

#define SWZ(row, slot) \
    ((slot) ^ ((row) & 3) ^ (((row) >> 2) & 3) ^ (((row) >> 5) & 1))

#define LDS_BARRIER()                                                \
    do {                                                             \
        asm volatile("s_waitcnt lgkmcnt(0)" ::: "memory");           \
        __builtin_amdgcn_s_barrier();                                \
        __builtin_amdgcn_sched_barrier(0);                           \
    } while (0)

// Prep: blocks [0,nT): transpose x -> xth [N][2][32] fp16; blocks [nT,nT+25):
// repack W -> Wrh[k][o][c] fp16.   (shared by both paths)
__global__ __launch_bounds__(256) void prep_all(const float* __restrict__ x,
                                                const float* __restrict__ W,
                                                unsigned short* __restrict__ xth,
                                                unsigned short* __restrict__ Wrh,
                                                int N, int nT) {
    int bid = blockIdx.x, tid = threadIdx.x;
    if (bid >= nT) {
        int k = bid - nT;  // 0..24
#pragma unroll
        for (int it = 0; it < 8; ++it) {
            int r = tid + 256 * it;          // 0..2047 = o*32+c
            int o = r >> 5, c = r & 31;
            __half h = __float2half(W[o * 800 + c * 25 + k]);
            Wrh[k * 2048 + r] = *reinterpret_cast<unsigned short*>(&h);
        }
        return;
    }
    __shared__ float t[2][32][65];
    int n0 = bid * 64;
#pragma unroll
    for (int i = 0; i < 16; ++i) {
        int e = tid + 256 * i;               // [2][32][64]
        int b = e >> 11, c = (e >> 6) & 31, nl = e & 63;
        int n = n0 + nl;
        t[b][c][nl] = (n < N) ? x[(size_t)(b * 32 + c) * N + n] : 0.f;
    }
    __syncthreads();
    int nl = tid >> 2, q = tid & 3, n = n0 + nl;
    if (n < N) {
#pragma unroll
        for (int b = 0; b < 2; ++b) {
            uint4 p;
            p.x = pack2h(t[b][q * 8 + 0][nl], t[b][q * 8 + 1][nl]);
            p.y = pack2h(t[b][q * 8 + 2][nl], t[b][q * 8 + 3][nl]);
            p.z = pack2h(t[b][q * 8 + 4][nl], t[b][q * 8 + 5][nl]);
            p.w = pack2h(t[b][q * 8 + 6][nl], t[b][q * 8 + 7][nl]);
            *reinterpret_cast<uint4*>(xth + ((size_t)n * 64 + b * 32 + q * 8)) = p;
        }
    }
}

// ===================== PHASE A: pure gather stream ==========================
// s[k][n][b][32c] fp16. 8 lanes per (n,k): 3 paired-line gathers -> hfma ->
// one coalesced 128B store. No LDS, no barriers, no MFMA — max TLP.
__global__ __launch_bounds__(256) void gather_s(
    const unsigned short* __restrict__ xth,  // [N][2][32] fp16
    const int* __restrict__ nidx,            // [N][25][3]
    const float* __restrict__ nw,            // [N][25][3]
    unsigned short* __restrict__ s,          // [25][N][2][32] fp16
    int N)
{
    const int tid = threadIdx.x;
    const int n0 = blockIdx.x * 32;
    const int nl = tid >> 3, p8 = tid & 7;
    const int n = n0 + nl;
    const int nc = (n < N) ? n : (N - 1);
    const bool wr = (n < N);

    const int*   ib = nidx + (size_t)nc * 75;
    const float* wb = nw   + (size_t)nc * 75;
    const unsigned short* xg = xth + p8 * 8;   // + j*64 per gather

    int3   ri[2];
    float3 rw[2];
    unsigned int rwh[2][3];
    uint4  rg[2][3];

    // prologue: gathers 0,1; idx/w 2,3 in flight
    {
        int3 i0 = *reinterpret_cast<const int3*>(ib + 0);
        float3 w0 = *reinterpret_cast<const float3*>(wb + 0);
        int3 i1 = *reinterpret_cast<const int3*>(ib + 3);
        float3 w1 = *reinterpret_cast<const float3*>(wb + 3);
        rg[0][0] = *reinterpret_cast<const uint4*>(xg + i0.x * 64);
        rg[0][1] = *reinterpret_cast<const uint4*>(xg + i0.y * 64);
        rg[0][2] = *reinterpret_cast<const uint4*>(xg + i0.z * 64);
        rg[1][0] = *reinterpret_cast<const uint4*>(xg + i1.x * 64);
        rg[1][1] = *reinterpret_cast<const uint4*>(xg + i1.y * 64);
        rg[1][2] = *reinterpret_cast<const uint4*>(xg + i1.z * 64);
        rwh[0][0] = pack2h(w0.x, w0.x); rwh[0][1] = pack2h(w0.y, w0.y);
        rwh[0][2] = pack2h(w0.z, w0.z);
        rwh[1][0] = pack2h(w1.x, w1.x); rwh[1][1] = pack2h(w1.y, w1.y);
        rwh[1][2] = pack2h(w1.z, w1.z);
        ri[0] = *reinterpret_cast<const int3*>(ib + 6);
        rw[0] = *reinterpret_cast<const float3*>(wb + 6);
        ri[1] = *reinterpret_cast<const int3*>(ib + 9);
        rw[1] = *reinterpret_cast<const float3*>(wb + 9);
    }

#pragma unroll
    for (int k = 0; k < 25; ++k) {
        const int gb = k & 1;

        __half2 w0 = u_as_h2(rwh[gb][0]), w1 = u_as_h2(rwh[gb][1]),
                w2 = u_as_h2(rwh[gb][2]);
        uint4 v0 = rg[gb][0], v1 = rg[gb][1], v2 = rg[gb][2];
        uint4 pk; U2H2 c;
        c.h = __hfma2(u_as_h2(v0.x), w0, __hfma2(u_as_h2(v1.x), w1, __hmul2(u_as_h2(v2.x), w2)));
        pk.x = c.u;
        c.h = __hfma2(u_as_h2(v0.y), w0, __hfma2(u_as_h2(v1.y), w1, __hmul2(u_as_h2(v2.y), w2)));
        pk.y = c.u;
        c.h = __hfma2(u_as_h2(v0.z), w0, __hfma2(u_as_h2(v1.z), w1, __hmul2(u_as_h2(v2.z), w2)));
        pk.z = c.u;
        c.h = __hfma2(u_as_h2(v0.w), w0, __hfma2(u_as_h2(v1.w), w1, __hmul2(u_as_h2(v2.w), w2)));
        pk.w = c.u;
        if (wr)
            *reinterpret_cast<uint4*>(s + ((size_t)k * N + n) * 64 + p8 * 8) = pk;

        // refill: gathers(k+2) from prefetched idx; idx/w(k+4)
        if (k + 2 < 25) {
            rg[gb][0] = *reinterpret_cast<const uint4*>(xg + ri[gb].x * 64);
            rg[gb][1] = *reinterpret_cast<const uint4*>(xg + ri[gb].y * 64);
            rg[gb][2] = *reinterpret_cast<const uint4*>(xg + ri[gb].z * 64);
            rwh[gb][0] = pack2h(rw[gb].x, rw[gb].x);
            rwh[gb][1] = pack2h(rw[gb].y, rw[gb].y);
            rwh[gb][2] = pack2h(rw[gb].z, rw[gb].z);
            int ka = (k + 4 <= 24) ? k + 4 : 24;
            ri[gb] = *reinterpret_cast<const int3*>(ib + ka * 3);
            rw[gb] = *reinterpret_cast<const float3*>(wb + ka * 3);
        }
    }
}

// ===================== PHASE B: dense streaming GEMM ========================
// Champion skeleton; sA filled from s with ONE sequential uint4 load per
// thread per slice (depth-3 prefetch, L3-resident stream). No idx, no hfma.
__global__ __launch_bounds__(256) void gemm_s(
    const unsigned short* __restrict__ s,    // [25][N][2][32] fp16
    const unsigned short* __restrict__ Wrh,  // [25][64][32] fp16
    const float* __restrict__ bias,          // [64]
    float* __restrict__ out,                 // [2][64][N] fp32
    int N)
{
    __shared__ __align__(16) unsigned char sA[2][4096];
    __shared__ __align__(16) unsigned char sB[2][4096];

    const int tid = threadIdx.x;
    const int n0 = blockIdx.x * 32;

    const int nl = tid >> 3, p8 = tid & 7;
    const int grow = (p8 >> 2) * 32 + nl;
    const int gq = p8 & 3;
    const int wr_off = grow * 64 + (SWZ(grow, gq) << 4);

    const int sbo = (tid >> 2) * 64 + (SWZ((tid >> 2), (tid & 3)) << 4);

    const int l = tid & 63, wv = tid >> 6, c16 = l & 15, g = l >> 4;
    const int arow = 16 * wv + c16;
    const int rd_a = arow * 64 + (SWZ(arow, g) << 4);

    const int nc = (n0 + nl < N) ? (n0 + nl) : (N - 1);   // clamped read row
    const unsigned short* sp = s + (size_t)nc * 64 + p8 * 8;  // + k*N*64 per k

    uint4 rs[3];
    uint4 rB;

    f32x4 acc[4];
#pragma unroll
    for (int ot = 0; ot < 4; ++ot) acc[ot] = (f32x4){0.f, 0.f, 0.f, 0.f};

    // prologue: B(0); s slices 0..2
    rB = *reinterpret_cast<const uint4*>(Wrh + tid * 8);
    rs[0] = *reinterpret_cast<const uint4*>(sp + (size_t)0 * N * 64);
    rs[1] = *reinterpret_cast<const uint4*>(sp + (size_t)1 * N * 64);
    rs[2] = *reinterpret_cast<const uint4*>(sp + (size_t)2 * N * 64);

#pragma unroll
    for (int k = 0; k < 25; ++k) {
        const int sb = k % 3, buf = k & 1;

        *reinterpret_cast<uint4*>(&sB[buf][sbo]) = rB;
        if (k + 1 < 25)
            rB = *reinterpret_cast<const uint4*>(Wrh + (k + 1) * 2048 + tid * 8);

        *reinterpret_cast<uint4*>(&sA[buf][wr_off]) = rs[sb];

        LDS_BARRIER();

        if (k + 3 < 25)
            rs[sb] = *reinterpret_cast<const uint4*>(sp + (size_t)(k + 3) * N * 64);

        {
            half8 af = *reinterpret_cast<const half8*>(&sA[buf][rd_a]);
#pragma unroll
            for (int ot = 0; ot < 4; ++ot) {
                int orow = ot * 16 + c16;
                half8 bf = *reinterpret_cast<const half8*>(
                    &sB[buf][orow * 64 + (SWZ(orow, g) << 4)]);
                acc[ot] = __builtin_amdgcn_mfma_f32_16x16x32_f16(af, bf, acc[ot], 0, 0, 0);
            }
        }
    }

#pragma unroll
    for (int ot = 0; ot < 4; ++ot) {
        int o = ot * 16 + c16;
        float bv = bias[o];
#pragma unroll
        for (int i = 0; i < 4; ++i) {
            int mrow = 16 * wv + 4 * g + i;
            int b = mrow >> 5, nn = n0 + (mrow & 31);
            if (nn < N) out[((size_t)b * 64 + o) * N + nn] = acc[ot][i] + bv;
        }
    }
}

// ===================== FALLBACK: proven champion (R16) ======================
__global__ __launch_bounds__(256) void fused_main(
    const unsigned short* __restrict__ xth,
    const unsigned short* __restrict__ Wrh,
    const float* __restrict__ bias,
    const int* __restrict__ nidx,
    const float* __restrict__ nw,
    float* __restrict__ out,
    int N)
{
    __shared__ unsigned int idxw[32 * 104];
    __shared__ __align__(16) unsigned char sA[2][4096];
    __shared__ __align__(16) unsigned char sB[2][4096];

    const int tid = threadIdx.x;
    const int n0 = blockIdx.x * 32;

#pragma unroll
    for (int it = 0; it < 13; ++it) {
        int e = tid + 256 * it;
        if (e < 3328) idxw[e] = 0u;
    }
    __syncthreads();
#pragma unroll
    for (int it = 0; it < 10; ++it) {
        int e = tid + 256 * it;
        if (e < 2400) {
            int nl = e / 75, r = e - nl * 75;
            int kk = r / 3, t = r - kk * 3;
            int n = n0 + nl;
            unsigned int u = 0;
            if (n < N) {
                size_t ss = (size_t)n0 * 75 + e;
                int j = nidx[ss];
                __half hw = __float2half(nw[ss]);
                u = (unsigned int)j |
                    ((unsigned int)*reinterpret_cast<unsigned short*>(&hw) << 16);
            }
            idxw[nl * 104 + kk * 4 + t] = u;
        }
    }
    __syncthreads();

    const int nl = tid >> 3;
    const int p8 = tid & 7;
    const int grow = (p8 >> 2) * 32 + nl;
    const int gq = p8 & 3;
    const int wr_off = grow * 64 + (SWZ(grow, gq) << 4);
    const int sbo = (tid >> 2) * 64 + (SWZ((tid >> 2), (tid & 3)) << 4);

    const int l = tid & 63, wv = tid >> 6, c16 = l & 15, g = l >> 4;
    const int arow = 16 * wv + c16;
    const int rd_a = arow * 64 + (SWZ(arow, g) << 4);

    const unsigned short* xg = xth + p8 * 8;
    const unsigned int* iprow = &idxw[nl * 104];

    unsigned int ru[3][3];
    uint4 rg[3][3];
    uint4 rB;

    f32x4 acc[4];
#pragma unroll
    for (int ot = 0; ot < 4; ++ot) acc[ot] = (f32x4){0.f, 0.f, 0.f, 0.f};

    rB = *reinterpret_cast<const uint4*>(Wrh + tid * 8);
#pragma unroll
    for (int kk = 0; kk < 3; ++kk) {
        uint4 iq = *reinterpret_cast<const uint4*>(iprow + kk * 4);
        ru[kk][0] = iq.x; ru[kk][1] = iq.y; ru[kk][2] = iq.z;
    }
#pragma unroll
    for (int kk = 0; kk < 3; ++kk)
#pragma unroll
        for (int t = 0; t < 3; ++t)
            rg[kk][t] = *reinterpret_cast<const uint4*>(xg + (ru[kk][t] & 0xffffu) * 64);

#pragma unroll
    for (int k = 0; k < 25; ++k) {
        const int gb = k % 3, buf = k & 1;

        *reinterpret_cast<uint4*>(&sB[buf][sbo]) = rB;
        if (k + 1 < 25)
            rB = *reinterpret_cast<const uint4*>(Wrh + (k + 1) * 2048 + tid * 8);

        {
            __half2 w0 = hi16(ru[gb][0]), w1 = hi16(ru[gb][1]), w2 = hi16(ru[gb][2]);
            uint4 v0 = rg[gb][0], v1 = rg[gb][1], v2 = rg[gb][2];
            uint4 pk; U2H2 c;
            c.h = __hfma2(u_as_h2(v0.x), w0, __hfma2(u_as_h2(v1.x), w1, __hmul2(u_as_h2(v2.x), w2)));
            pk.x = c.u;
            c.h = __hfma2(u_as_h2(v0.y), w0, __hfma2(u_as_h2(v1.y), w1, __hmul2(u_as_h2(v2.y), w2)));
            pk.y = c.u;
            c.h = __hfma2(u_as_h2(v0.z), w0, __hfma2(u_as_h2(v1.z), w1, __hmul2(u_as_h2(v2.z), w2)));
            pk.z = c.u;
            c.h = __hfma2(u_as_h2(v0.w), w0, __hfma2(u_as_h2(v1.w), w1, __hmul2(u_as_h2(v2.w), w2)));
            pk.w = c.u;
            *reinterpret_cast<uint4*>(&sA[buf][wr_off]) = pk;
        }

        uint4 niq;
        {
            int ka = (k + 3 < 25) ? k + 3 : 25;
            niq = *reinterpret_cast<const uint4*>(iprow + ka * 4);
        }

        LDS_BARRIER();

        if (k + 3 < 25) {
            ru[gb][0] = niq.x; ru[gb][1] = niq.y; ru[gb][2] = niq.z;
#pragma unroll
            for (int t = 0; t < 3; ++t)
                rg[gb][t] = *reinterpret_cast<const uint4*>(xg + (ru[gb][t] & 0xffffu) * 64);
        }

        {
            half8 af = *reinterpret_cast<const half8*>(&sA[buf][rd_a]);
#pragma unroll
            for (int ot = 0; ot < 4; ++ot) {
                int orow = ot * 16 + c16;
                half8 bf = *reinterpret_cast<const half8*>(
                    &sB[buf][orow * 64 + (SWZ(orow, g) << 4)]);
                acc[ot] = __builtin_amdgcn_mfma_f32_16x16x32_f16(af, bf, acc[ot], 0, 0, 0);
            }
        }
    }

#pragma unroll
    for (int ot = 0; ot < 4; ++ot) {
        int o = ot * 16 + c16;
        float bv = bias[o];
#pragma unroll
        for (int i = 0; i < 4; ++i) {
            int mrow = 16 * wv + 4 * g + i;
            int b = mrow >> 5, nn = n0 + (mrow & 31);
            if (nn < N) out[((size_t)b * 64 + o) * N + nn] = acc[ot][i] + bv;
        }
    }
}

extern "C" void kernel_launch(void* const* d_in, const int* in_sizes, int n_in,
                              void* d_out, int out_size, void* d_ws, size_t ws_size,
                              hipStream_t stream) {
    const float* x    = (const float*)d_in[0];   // (2,32,N)
    const float* nw   = (const float*)d_in[1];   // (N,25,3)
    const float* W    = (const float*)d_in[2];   // (64,800)
    const float* bias = (const float*)d_in[3];   // (64,)
    const int*   nidx = (const int*)d_in[4];     // (N,25,3)
    float* out = (float*)d_out;

    int N = in_sizes[0] / 64;  // B*C = 64

    unsigned short* xth = (unsigned short*)d_ws;      // [N][2][32] fp16
    unsigned short* Wrh = xth + (size_t)N * 64;       // [25][64][32] fp16
    unsigned short* s   = Wrh + 51200;                // [25][N][2][32] fp16

    size_t need = ((size_t)N * 64 + 51200 + (size_t)N * 25 * 64 + 2048)
                  * sizeof(unsigned short);

    int nT = (N + 63) / 64;
    prep_all<<<nT + 25, 256, 0, stream>>>(x, W, xth, Wrh, N, nT);

    int nblk = (N + 31) / 32;
    if (ws_size >= need) {
        gather_s<<<nblk, 256, 0, stream>>>(xth, nidx, nw, s, N);
        gemm_s<<<nblk, 256, 0, stream>>>(s, Wrh, bias, out, N);
    } else {
        fused_main<<<nblk, 256, 0, stream>>>(xth, Wrh, bias, nidx, nw, out, N);
    }
}